// Round 10
// baseline (239.391 us; speedup 1.0000x reference)
//
#include <hip/hip_runtime.h>
#include <hip/hip_bf16.h>

// GroupedVectorSA (gfx950) — ROUND 10: 2 launches (k_qkv self-staged + prep blocks
// fused in), v_cvt_pk_bf16_f32 packs, q/v prefetch, bias-initialized accumulators.

typedef __attribute__((ext_vector_type(8))) short bf16x8_t;
typedef __attribute__((ext_vector_type(4))) float f32x4_t;

#define BN_EPS 1e-5f
#define WSYNC() asm volatile("s_waitcnt lgkmcnt(0)" ::: "memory")

__device__ __forceinline__ float blo(unsigned int v) {
    union { unsigned int u; float f; } x; x.u = v << 16; return x.f;
}
__device__ __forceinline__ float bhi(unsigned int v) {
    union { unsigned int u; float f; } x; x.u = v & 0xffff0000u; return x.f;
}
__device__ __forceinline__ unsigned int fbits(float f) {
    union { float f; unsigned int u; } x; x.f = f; return x.u;
}
__device__ __forceinline__ unsigned short f2b(float f) {      // RNE fp32->bf16
    unsigned int u = fbits(f);
    return (unsigned short)((u + 0x7fffu + ((u >> 16) & 1u)) >> 16);
}
// RNE pack pair {lo:a, hi:b} via v_cvt_pk_bf16_f32 (gfx950)
__device__ __forceinline__ unsigned int f2bpk(float a, float b) {
    union { __hip_bfloat162 h; unsigned int u; } x;
    x.h = __float22bfloat162_rn(make_float2(a, b));
    return x.u;
}
__device__ __forceinline__ unsigned int relpair(unsigned int kb, unsigned int qb,
                                                unsigned int pm_, unsigned int pb_) {
    float r0 = (blo(kb) - blo(qb)) * blo(pm_) + blo(pb_);
    float r1 = (bhi(kb) - bhi(qb)) * bhi(pm_) + bhi(pb_);
    return f2bpk(r0, r1);
}

// ---------------------------------------------------------------------------
// K1: fused q/k/v GEMM + prep.
//  bid < 768 : compute. widx=bid/256, rem=bid&255, nh=rem&1, mb=rem>>1 (64-row tile).
//              Stages its W-half as LDS [nloc][k] bf16 (stride 264) from fp32 W.
//  768..831  : pm_w2/pb_w2 -> frag-linear bf16 in wsT slots 3,4 (for k_main).
//  832       : W4 folded pos-MLP layer-1 coeffs.   833: we1TF (we_w1^T bf16).
// ---------------------------------------------------------------------------
__global__ __launch_bounds__(256) void k_qkv(
    const float* __restrict__ feats,
    const float* __restrict__ wq, const float* __restrict__ bq, const float* __restrict__ bnq,
    const float* __restrict__ wk, const float* __restrict__ bk, const float* __restrict__ bnk,
    const float* __restrict__ wv, const float* __restrict__ bv,
    const float* __restrict__ pm2, const float* __restrict__ pb2,
    const float* __restrict__ pm_w1, const float* __restrict__ pm_b1, const float* __restrict__ pm_bn,
    const float* __restrict__ pb_w1, const float* __restrict__ pb_b1, const float* __restrict__ pb_bn,
    const float* __restrict__ we_w1,
    unsigned short* __restrict__ qkv, unsigned short* __restrict__ wsT,
    float* __restrict__ W4, unsigned short* __restrict__ we1TF)
{
    __shared__ __align__(16) unsigned short LSH[128 * 264];   // 66 KB
    const int bid = blockIdx.x, t = threadIdx.x;

    if (bid >= 768) {
        if (bid < 832) {                       // frag-linear transform of pm2/pb2
            unsigned short (*T)[72] = (unsigned short(*)[72])LSH;
            int bp  = bid - 768;
            int mat = 3 + (bp >> 5);
            int sub = bp & 31;
            int kk  = sub >> 2, ntq = sub & 3;
            const float* s = (mat == 3) ? pm2 : pb2;
            {
                int c = t & 63, r0 = t >> 6;
                for (int i = 0; i < 8; ++i) {
                    int r = r0 + i * 4;
                    T[r][c] = f2b(s[(kk * 32 + r) * 256 + ntq * 64 + c]);
                }
            }
            __syncthreads();
            {
                int seg = t >> 6, lane = t & 63;
                int col = seg * 16 + (lane & 15);
                int kr  = (lane >> 4) * 8;
                unsigned int v[8];
                #pragma unroll
                for (int j = 0; j < 8; ++j) v[j] = T[kr + j][col];
                uint4 o;
                o.x = v[0] | (v[1] << 16);
                o.y = v[2] | (v[3] << 16);
                o.z = v[4] | (v[5] << 16);
                o.w = v[6] | (v[7] << 16);
                *(uint4*)(wsT + mat * 65536 + (ntq * 4 + seg) * 4096 + kk * 512 + lane * 8) = o;
            }
        } else if (bid == 832) {
            int c = t;
            float s = pm_bn[c] / sqrtf(pm_bn[768 + c] + BN_EPS);
            float4 wm = make_float4(pm_w1[c] * s, pm_w1[256 + c] * s, pm_w1[512 + c] * s,
                                    (pm_b1[c] - pm_bn[512 + c]) * s + pm_bn[256 + c]);
            s = pb_bn[c] / sqrtf(pb_bn[768 + c] + BN_EPS);
            float4 wb = make_float4(pb_w1[c] * s, pb_w1[256 + c] * s, pb_w1[512 + c] * s,
                                    (pb_b1[c] - pb_bn[512 + c]) * s + pb_bn[256 + c]);
            ((float4*)W4)[c]       = wm;
            ((float4*)W4)[256 + c] = wb;
        } else {
            for (int j = 0; j < 8; ++j) {
                int e = t * 8 + j;
                int g = e >> 8, c = e & 255;
                we1TF[g * 256 + c] = f2b(we_w1[c * 8 + g]);
            }
        }
        return;
    }

    // ------------------- compute block -------------------
    const int widx = bid >> 8;
    const int rem  = bid & 255;
    const int nh   = rem & 1;
    const int mb   = rem >> 1;                 // rows mb*64 .. mb*64+63

    const float* W    = (widx == 0) ? wq : (widx == 1) ? wk : wv;
    const float* bias = (widx == 0) ? bq : (widx == 1) ? bk : bv;
    const float* bn   = (widx == 0) ? bnq : (widx == 1) ? bnk : nullptr;
    unsigned short* dst = qkv + (size_t)widx * 8192 * 256;

    const int lane = t & 63, w = t >> 6;
    const int ln15 = lane & 15, quad = lane >> 4;

    // A-frags for this wave's 16 rows (global fp32 -> pk-bf16), issued first
    bf16x8_t afr[8];
    {
        int row = mb * 64 + w * 16 + ln15;
        #pragma unroll
        for (int kk = 0; kk < 8; ++kk) {
            const float* p = feats + row * 256 + kk * 32 + quad * 8;
            float4 fa = *(const float4*)p;
            float4 fb = *(const float4*)(p + 4);
            union { unsigned int u[4]; bf16x8_t v; } x;
            x.u[0] = f2bpk(fa.x, fa.y);
            x.u[1] = f2bpk(fa.z, fa.w);
            x.u[2] = f2bpk(fb.x, fb.y);
            x.u[3] = f2bpk(fb.z, fb.w);
            afr[kk] = x.v;
        }
    }
    // epilogue fold per col (y = acc*sc + dd; relu unless v)
    float scv[8], ddv[8];
    #pragma unroll
    for (int j = 0; j < 8; ++j) {
        int c = nh * 128 + j * 16 + ln15;
        float bb = bias[c];
        if (bn) {
            float s = bn[c] / sqrtf(bn[768 + c] + BN_EPS);
            scv[j] = s;
            ddv[j] = (bb - bn[512 + c]) * s + bn[256 + c];
        } else { scv[j] = 1.f; ddv[j] = bb; }
    }

    // stage W-half: LSH[nloc][k] (stride 264) = bf16(W[k][nh*128+nloc])
    {
        const int nloc = t & 127, kq = t >> 7;
        const float* Wb = W + nh * 128 + nloc;
        for (int it = 0; it < 32; ++it) {
            int k0 = it * 8 + kq * 4;
            float w0 = Wb[(k0    ) * 256];
            float w1 = Wb[(k0 + 1) * 256];
            float w2 = Wb[(k0 + 2) * 256];
            float w3 = Wb[(k0 + 3) * 256];
            *(uint2*)&LSH[nloc * 264 + k0] = make_uint2(f2bpk(w0, w1), f2bpk(w2, w3));
        }
    }
    __syncthreads();

    // MFMA: acc over 8 local nt bands
    f32x4_t acc[8];
    #pragma unroll
    for (int j = 0; j < 8; ++j) acc[j] = (f32x4_t){0.f, 0.f, 0.f, 0.f};
    #pragma unroll
    for (int kk = 0; kk < 8; ++kk) {
        #pragma unroll
        for (int j = 0; j < 8; ++j) {
            bf16x8_t bfr = *(const bf16x8_t*)&LSH[(j * 16 + ln15) * 264 + kk * 32 + quad * 8];
            acc[j] = __builtin_amdgcn_mfma_f32_16x16x32_bf16(afr[kk], bfr, acc[j], 0, 0, 0);
        }
    }
    __syncthreads();                           // LSH (W) reads done

    // epilogue -> Ct (reuse LSH, stride 136), then coalesced store
    unsigned short (*Ct)[136] = (unsigned short(*)[136])LSH;
    #pragma unroll
    for (int j = 0; j < 8; ++j) {
        float y[4];
        #pragma unroll
        for (int r = 0; r < 4; ++r) {
            y[r] = acc[j][r] * scv[j] + ddv[j];
            if (bn) y[r] = fmaxf(y[r], 0.f);
        }
        int cl = j * 16 + ln15;
        for (int r = 0; r < 4; r += 2) {
            unsigned int pk = f2bpk(y[r], y[r + 1]);
            Ct[w * 16 + quad * 4 + r][cl]     = (unsigned short)pk;
            Ct[w * 16 + quad * 4 + r + 1][cl] = (unsigned short)(pk >> 16);
        }
    }
    __syncthreads();
    {
        int row = t >> 2, c0 = (t & 3) * 32;
        uint4 v0 = *(const uint4*)&Ct[row][c0];
        uint4 v1 = *(const uint4*)&Ct[row][c0 + 8];
        uint4 v2 = *(const uint4*)&Ct[row][c0 + 16];
        uint4 v3 = *(const uint4*)&Ct[row][c0 + 24];
        unsigned short* d = dst + (mb * 64 + row) * 256 + nh * 128 + c0;
        *(uint4*)(d)      = v0;
        *(uint4*)(d + 8)  = v1;
        *(uint4*)(d + 16) = v2;
        *(uint4*)(d + 24) = v3;
    }
}

// ---------------------------------------------------------------------------
// K2: fused main. 1 WG = 4 points, wave w owns point w. blk=256, grid=2048.
// ---------------------------------------------------------------------------
__global__ __launch_bounds__(256, 2) void k_main(
    const float* __restrict__ coords,
    const int*   __restrict__ index,
    const unsigned short* __restrict__ qm,
    const unsigned short* __restrict__ km,
    const unsigned short* __restrict__ vm,
    const unsigned short* __restrict__ pmw2F,
    const unsigned short* __restrict__ pbw2F,
    const float* __restrict__ W4,
    const unsigned short* __restrict__ we1TF,
    const float* __restrict__ pm_b2, const float* __restrict__ pb_b2,
    const float* __restrict__ we_b1, const float* __restrict__ we_bn,
    const float* __restrict__ we_w2, const float* __restrict__ we_b2,
    float* __restrict__ out)
{
    __shared__ unsigned short bufR[64][264];   // h0 -> h1 -> pem
    __shared__ unsigned short bufP[64][264];   // peb
    __shared__ float posA[64][4];
    __shared__ float us_[64][8];
    __shared__ float we2s[8][8];
    __shared__ float web2[8];

    const int t  = threadIdx.x;
    const int P0 = blockIdx.x * 4;
    const int bb_ = P0 >> 12;
    const int w = t >> 6, lane = t & 63;
    const int ln15 = lane & 15, quad = lane >> 4;
    const int R0 = w * 16;
    const int Pg = P0 + w;

    // ---- prefetches (LDS-bound occupancy -> VGPRs are free) ----
    const int rg = (bb_ << 12) + index[Pg * 16 + ln15];
    uint4 kpre[8], qpre[8];
    #pragma unroll
    for (int kk = 0; kk < 8; ++kk) {
        kpre[kk] = *(const uint4*)(km + rg * 256 + kk * 32 + quad * 8);
        qpre[kk] = *(const uint4*)(qm + Pg * 256 + kk * 32 + quad * 8);
    }
    uint2 vpre[16];
    #pragma unroll
    for (int s = 0; s < 16; ++s) {
        int rv = (bb_ << 12) + index[Pg * 16 + s];
        vpre[s] = *(const uint2*)(vm + rv * 256 + lane * 4);
    }
    // bias prefetch for acc init
    float bb0[4], bb1[4];
    #pragma unroll
    for (int ntl = 0; ntl < 4; ++ntl) {
        int c = (w * 4 + ntl) * 16 + ln15;
        bb0[ntl] = pb_b2[c];
        bb1[ntl] = pm_b2[c];
    }
    // per-lane folded layer-1 coeffs (4 cols)
    const int hc = lane * 4;
    float4 cm[4], cb[4];
    #pragma unroll
    for (int i = 0; i < 4; ++i) {
        cm[i] = ((const float4*)W4)[hc + i];
        cb[i] = ((const float4*)W4)[256 + hc + i];
    }
    // logits BN fold
    const int g8 = ln15 & 7;
    const float swe_r = we_bn[g8] / sqrtf(we_bn[24 + g8] + BN_EPS);
    const float dwe_r = (we_b1[g8] - we_bn[16 + g8]) * swe_r + we_bn[8 + g8];

    if (lane < 16) {
        int rgs = (bb_ << 12) + index[Pg * 16 + lane];
        posA[R0 + lane][0] = coords[Pg * 3 + 0] - coords[rgs * 3 + 0];
        posA[R0 + lane][1] = coords[Pg * 3 + 1] - coords[rgs * 3 + 1];
        posA[R0 + lane][2] = coords[Pg * 3 + 2] - coords[rgs * 3 + 2];
        posA[R0 + lane][3] = 0.f;
    }
    if (t < 64) we2s[t >> 3][t & 7] = we_w2[t];
    if (t < 8)  web2[t] = we_b2[t];
    WSYNC();

    // ---- h0 (pb hidden): own 16 rows x 4 cols ----
    #pragma unroll
    for (int m = 0; m < 16; ++m) {
        float4 p = *(const float4*)&posA[R0 + m][0];
        float h0 = fmaxf(p.x * cb[0].x + p.y * cb[0].y + p.z * cb[0].z + cb[0].w, 0.f);
        float h1 = fmaxf(p.x * cb[1].x + p.y * cb[1].y + p.z * cb[1].z + cb[1].w, 0.f);
        float h2 = fmaxf(p.x * cb[2].x + p.y * cb[2].y + p.z * cb[2].z + cb[2].w, 0.f);
        float h3 = fmaxf(p.x * cb[3].x + p.y * cb[3].y + p.z * cb[3].z + cb[3].w, 0.f);
        *(uint2*)&bufR[R0 + m][hc] = make_uint2(f2bpk(h0, h1), f2bpk(h2, h3));
    }
    __syncthreads();                           // B1

    // ---- pass0 MFMA: peb (acc init = bias) ----
    f32x4_t acc[4][4];
    #pragma unroll
    for (int a = 0; a < 4; ++a)
        for (int mt = 0; mt < 4; ++mt)
            acc[a][mt] = (f32x4_t){bb0[a], bb0[a], bb0[a], bb0[a]};
    #pragma unroll
    for (int kk = 0; kk < 8; ++kk) {
        bf16x8_t afr[4];
        #pragma unroll
        for (int mt = 0; mt < 4; ++mt)
            afr[mt] = *(const bf16x8_t*)&bufR[mt * 16 + ln15][kk * 32 + quad * 8];
        #pragma unroll
        for (int ntl = 0; ntl < 4; ++ntl) {
            int nt = w * 4 + ntl;
            bf16x8_t bfr = *(const bf16x8_t*)(pbw2F + ((nt * 8 + kk) * 64 + lane) * 8);
            #pragma unroll
            for (int mt = 0; mt < 4; ++mt)
                acc[ntl][mt] = __builtin_amdgcn_mfma_f32_16x16x32_bf16(afr[mt], bfr, acc[ntl][mt], 0, 0, 0);
        }
    }
    __syncthreads();                           // B2

    // peb epilogue -> bufP
    #pragma unroll
    for (int ntl = 0; ntl < 4; ++ntl) {
        int c = (w * 4 + ntl) * 16 + ln15;
        for (int mt = 0; mt < 4; ++mt)
            for (int r = 0; r < 4; r += 2) {
                unsigned int pk = f2bpk(acc[ntl][mt][r], acc[ntl][mt][r + 1]);
                bufP[mt * 16 + quad * 4 + r][c]     = (unsigned short)pk;
                bufP[mt * 16 + quad * 4 + r + 1][c] = (unsigned short)(pk >> 16);
            }
    }
    // h1 (pm hidden) -> bufR
    #pragma unroll
    for (int m = 0; m < 16; ++m) {
        float4 p = *(const float4*)&posA[R0 + m][0];
        float h0 = fmaxf(p.x * cm[0].x + p.y * cm[0].y + p.z * cm[0].z + cm[0].w, 0.f);
        float h1 = fmaxf(p.x * cm[1].x + p.y * cm[1].y + p.z * cm[1].z + cm[1].w, 0.f);
        float h2 = fmaxf(p.x * cm[2].x + p.y * cm[2].y + p.z * cm[2].z + cm[2].w, 0.f);
        float h3 = fmaxf(p.x * cm[3].x + p.y * cm[3].y + p.z * cm[3].z + cm[3].w, 0.f);
        *(uint2*)&bufR[R0 + m][hc] = make_uint2(f2bpk(h0, h1), f2bpk(h2, h3));
    }
    __syncthreads();                           // B3

    // ---- pass1 MFMA: pem ----
    #pragma unroll
    for (int a = 0; a < 4; ++a)
        for (int mt = 0; mt < 4; ++mt)
            acc[a][mt] = (f32x4_t){bb1[a], bb1[a], bb1[a], bb1[a]};
    #pragma unroll
    for (int kk = 0; kk < 8; ++kk) {
        bf16x8_t afr[4];
        #pragma unroll
        for (int mt = 0; mt < 4; ++mt)
            afr[mt] = *(const bf16x8_t*)&bufR[mt * 16 + ln15][kk * 32 + quad * 8];
        #pragma unroll
        for (int ntl = 0; ntl < 4; ++ntl) {
            int nt = w * 4 + ntl;
            bf16x8_t bfr = *(const bf16x8_t*)(pmw2F + ((nt * 8 + kk) * 64 + lane) * 8);
            #pragma unroll
            for (int mt = 0; mt < 4; ++mt)
                acc[ntl][mt] = __builtin_amdgcn_mfma_f32_16x16x32_bf16(afr[mt], bfr, acc[ntl][mt], 0, 0, 0);
        }
    }
    __syncthreads();                           // B4

    // pem epilogue -> bufR
    #pragma unroll
    for (int ntl = 0; ntl < 4; ++ntl) {
        int c = (w * 4 + ntl) * 16 + ln15;
        for (int mt = 0; mt < 4; ++mt)
            for (int r = 0; r < 4; r += 2) {
                unsigned int pk = f2bpk(acc[ntl][mt][r], acc[ntl][mt][r + 1]);
                bufR[mt * 16 + quad * 4 + r][c]     = (unsigned short)pk;
                bufR[mt * 16 + quad * 4 + r + 1][c] = (unsigned short)(pk >> 16);
            }
    }
    __syncthreads();                           // B5

    // ---- relation + logits fused in registers ----
    {
        const bf16x8_t bz = {0, 0, 0, 0, 0, 0, 0, 0};
        f32x4_t lacc = {0.f, 0.f, 0.f, 0.f};
        #pragma unroll
        for (int kk = 0; kk < 8; ++kk) {
            int cb8 = kk * 32 + quad * 8;
            uint4 pm4 = *(const uint4*)&bufR[R0 + ln15][cb8];
            uint4 pb4 = *(const uint4*)&bufP[R0 + ln15][cb8];
            union { uint4 u; bf16x8_t v; } rr;
            rr.u.x = relpair(kpre[kk].x, qpre[kk].x, pm4.x, pb4.x);
            rr.u.y = relpair(kpre[kk].y, qpre[kk].y, pm4.y, pb4.y);
            rr.u.z = relpair(kpre[kk].z, qpre[kk].z, pm4.z, pb4.z);
            rr.u.w = relpair(kpre[kk].w, qpre[kk].w, pm4.w, pb4.w);
            bf16x8_t bfr = bz;
            if (ln15 < 8) bfr = *(const bf16x8_t*)(we1TF + ln15 * 256 + cb8);
            lacc = __builtin_amdgcn_mfma_f32_16x16x32_bf16(rr.v, bfr, lacc, 0, 0, 0);
        }
        if (ln15 < 8) {
            #pragma unroll
            for (int r = 0; r < 4; ++r)
                us_[R0 + quad * 4 + r][ln15] = fmaxf(lacc[r] * swe_r + dwe_r, 0.f);
        }
    }
    WSYNC();

    // ---- logits2 = u @ we_w2 + we_b2 ----
    if (lane < 16) {
        float uv[8], l[8];
        #pragma unroll
        for (int gp = 0; gp < 8; ++gp) uv[gp] = us_[R0 + lane][gp];
        #pragma unroll
        for (int g = 0; g < 8; ++g) {
            float x = web2[g];
            for (int gp = 0; gp < 8; ++gp) x += uv[gp] * we2s[gp][g];
            l[g] = x;
        }
        #pragma unroll
        for (int g = 0; g < 8; ++g) us_[R0 + lane][g] = l[g];
    }
    WSYNC();

    // ---- softmax over s ----
    if (lane < 8) {
        int g = lane;
        float mx = -1e30f;
        for (int s = 0; s < 16; ++s) mx = fmaxf(mx, us_[R0 + s][g]);
        float e[16], sum = 0.f;
        for (int s = 0; s < 16; ++s) { e[s] = __expf(us_[R0 + s][g] - mx); sum += e[s]; }
        float inv = 1.f / sum;
        for (int s = 0; s < 16; ++s) us_[R0 + s][g] = e[s] * inv;
    }
    WSYNC();

    // ---- output ----
    {
        int c5 = lane * 4, g = lane >> 3;
        float a0 = 0.f, a1 = 0.f, a2 = 0.f, a3 = 0.f;
        #pragma unroll
        for (int s = 0; s < 16; ++s) {
            float wv_ = us_[R0 + s][g];
            uint2 v4 = vpre[s];
            uint2 p4 = *(const uint2*)&bufP[R0 + s][c5];
            a0 += wv_ * (blo(v4.x) + blo(p4.x));
            a1 += wv_ * (bhi(v4.x) + bhi(p4.x));
            a2 += wv_ * (blo(v4.y) + blo(p4.y));
            a3 += wv_ * (bhi(v4.y) + bhi(p4.y));
        }
        *(float4*)(out + (size_t)Pg * 256 + c5) = make_float4(a0, a1, a2, a3);
    }
}

// ---------------------------------------------------------------------------
extern "C" void kernel_launch(void* const* d_in, const int* in_sizes, int n_in,
                              void* d_out, int out_size, void* d_ws, size_t ws_size,
                              hipStream_t stream)
{
    const float* feats  = (const float*)d_in[0];
    const float* coords = (const float*)d_in[1];
    const int*   index  = (const int*)d_in[2];
    const float* wq     = (const float*)d_in[3];
    const float* bq     = (const float*)d_in[4];
    const float* bnq    = (const float*)d_in[5];
    const float* wk     = (const float*)d_in[6];
    const float* bk     = (const float*)d_in[7];
    const float* bnk    = (const float*)d_in[8];
    const float* wv     = (const float*)d_in[9];
    const float* bv     = (const float*)d_in[10];
    const float* pm_w1  = (const float*)d_in[11];
    const float* pm_b1  = (const float*)d_in[12];
    const float* pm_bn  = (const float*)d_in[13];
    const float* pm_w2  = (const float*)d_in[14];
    const float* pm_b2  = (const float*)d_in[15];
    const float* pb_w1  = (const float*)d_in[16];
    const float* pb_b1  = (const float*)d_in[17];
    const float* pb_bn  = (const float*)d_in[18];
    const float* pb_w2  = (const float*)d_in[19];
    const float* pb_b2  = (const float*)d_in[20];
    const float* we_w1  = (const float*)d_in[21];
    const float* we_b1  = (const float*)d_in[22];
    const float* we_bn  = (const float*)d_in[23];
    const float* we_w2  = (const float*)d_in[24];
    const float* we_b2  = (const float*)d_in[25];

    unsigned short* qkv   = (unsigned short*)d_ws;                    // 12.58 MB
    unsigned short* wsT   = qkv + (size_t)3 * 8192 * 256;             // 640 KB (slots 3,4 used)
    float*          W4    = (float*)(wsT + 5 * 65536);                // 8 KB
    unsigned short* we1TF = (unsigned short*)(W4 + 2048);             // 4 KB

    const size_t need = (size_t)13238272 + 8192 + 4096;
    if (ws_size < need) {
        hipMemsetAsync(d_out, 0, (size_t)out_size * 4, stream);
        return;
    }

    k_qkv <<<834,  256, 0, stream>>>(feats,
                                     wq, bq, bnq, wk, bk, bnk, wv, bv,
                                     pm_w2, pb_w2,
                                     pm_w1, pm_b1, pm_bn,
                                     pb_w1, pb_b1, pb_bn,
                                     we_w1,
                                     qkv, wsT, W4, we1TF);
    k_main<<<2048, 256, 0, stream>>>(coords, index,
                                     qkv,
                                     qkv + (size_t)8192 * 256,
                                     qkv + (size_t)2 * 8192 * 256,
                                     wsT + 3 * 65536,
                                     wsT + 4 * 65536,
                                     W4, we1TF,
                                     pm_b2, pb_b2,
                                     we_b1, we_bn, we_w2, we_b2,
                                     (float*)d_out);
}

// Round 11
// 201.851 us; speedup vs baseline: 1.1860x; 1.1860x over previous
//
#include <hip/hip_runtime.h>
#include <hip/hip_bf16.h>

// GroupedVectorSA (gfx950) — ROUND 11: R9 structure (no spills) + hw bf16 pack
// + bias-initialized accumulators. 3 launches.

typedef __attribute__((ext_vector_type(8))) short bf16x8_t;
typedef __attribute__((ext_vector_type(4))) float f32x4_t;

#define BN_EPS 1e-5f
#define WSYNC() asm volatile("s_waitcnt lgkmcnt(0)" ::: "memory")

__device__ __forceinline__ float blo(unsigned int v) {
    union { unsigned int u; float f; } x; x.u = v << 16; return x.f;
}
__device__ __forceinline__ float bhi(unsigned int v) {
    union { unsigned int u; float f; } x; x.u = v & 0xffff0000u; return x.f;
}
__device__ __forceinline__ unsigned int fbits(float f) {
    union { float f; unsigned int u; } x; x.f = f; return x.u;
}
__device__ __forceinline__ unsigned short f2b(float f) {      // RNE fp32->bf16
    unsigned int u = fbits(f);
    return (unsigned short)((u + 0x7fffu + ((u >> 16) & 1u)) >> 16);
}
// RNE pack pair {lo:a, hi:b} — hardware packed convert on gfx950
__device__ __forceinline__ unsigned int f2bpk(float a, float b) {
    union { __hip_bfloat162 h; unsigned int u; } x;
    x.h = __float22bfloat162_rn(make_float2(a, b));
    return x.u;
}
__device__ __forceinline__ unsigned int relpair(unsigned int kb, unsigned int qb,
                                                unsigned int pm_, unsigned int pb_) {
    float r0 = (blo(kb) - blo(qb)) * blo(pm_) + blo(pb_);
    float r1 = (bhi(kb) - bhi(qb)) * bhi(pm_) + bhi(pb_);
    return f2bpk(r0, r1);
}

// ---------------------------------------------------------------------------
// K0: blocks 0..159: 5 weights -> bf16 fragment-linear (LDS transpose).
//     block 160: W4 folded pos-MLP layer-1 coeffs. block 161: we1TF.
// ---------------------------------------------------------------------------
__global__ __launch_bounds__(256) void k_prep(
    const float* __restrict__ wq, const float* __restrict__ wk,
    const float* __restrict__ wv, const float* __restrict__ pm2,
    const float* __restrict__ pb2,
    const float* __restrict__ pm_w1, const float* __restrict__ pm_b1,
    const float* __restrict__ pm_bn,
    const float* __restrict__ pb_w1, const float* __restrict__ pb_b1,
    const float* __restrict__ pb_bn,
    const float* __restrict__ we_w1,
    unsigned short* __restrict__ wsT, float* __restrict__ W4,
    unsigned short* __restrict__ we1TF)
{
    const int bid = blockIdx.x, t = threadIdx.x;
    if (bid < 160) {
        __shared__ unsigned short T[32][72];
        const int mat = bid >> 5;
        const int kk  = (bid >> 2) & 7;
        const int ntq = bid & 3;
        const float* s = (mat == 0) ? wq : (mat == 1) ? wk : (mat == 2) ? wv
                         : (mat == 3) ? pm2 : pb2;
        {
            int c = t & 63, r0 = t >> 6;
            for (int i = 0; i < 8; ++i) {
                int r = r0 + i * 4;
                T[r][c] = f2b(s[(kk * 32 + r) * 256 + ntq * 64 + c]);
            }
        }
        __syncthreads();
        {
            int seg = t >> 6, lane = t & 63;
            int col = seg * 16 + (lane & 15);
            int kr  = (lane >> 4) * 8;
            unsigned int v[8];
            #pragma unroll
            for (int j = 0; j < 8; ++j) v[j] = T[kr + j][col];
            uint4 o;
            o.x = v[0] | (v[1] << 16);
            o.y = v[2] | (v[3] << 16);
            o.z = v[4] | (v[5] << 16);
            o.w = v[6] | (v[7] << 16);
            *(uint4*)(wsT + mat * 65536 + (ntq * 4 + seg) * 4096 + kk * 512 + lane * 8) = o;
        }
    } else if (bid == 160) {
        int c = t;
        float s = pm_bn[c] / sqrtf(pm_bn[768 + c] + BN_EPS);
        float4 wm = make_float4(pm_w1[c] * s, pm_w1[256 + c] * s, pm_w1[512 + c] * s,
                                (pm_b1[c] - pm_bn[512 + c]) * s + pm_bn[256 + c]);
        s = pb_bn[c] / sqrtf(pb_bn[768 + c] + BN_EPS);
        float4 wb = make_float4(pb_w1[c] * s, pb_w1[256 + c] * s, pb_w1[512 + c] * s,
                                (pb_b1[c] - pb_bn[512 + c]) * s + pb_bn[256 + c]);
        ((float4*)W4)[c]       = wm;
        ((float4*)W4)[256 + c] = wb;
    } else {
        for (int j = 0; j < 8; ++j) {
            int e = t * 8 + j;
            int g = e >> 8, c = e & 255;
            we1TF[g * 256 + c] = f2b(we_w1[c * 8 + g]);
        }
    }
}

// ---------------------------------------------------------------------------
// K1: q/k/v GEMM. grid=768 (widx = bid>>8, mb = bid&255), blk=256.
// ---------------------------------------------------------------------------
__global__ __launch_bounds__(256) void k_qkv(
    const float* __restrict__ feats,
    const unsigned short* __restrict__ wT,
    const float* __restrict__ bq, const float* __restrict__ bnq,
    const float* __restrict__ bk, const float* __restrict__ bnk,
    const float* __restrict__ bv,
    unsigned short* __restrict__ qkv)
{
    __shared__ unsigned short A[32][264];
    const int t    = threadIdx.x;
    const int widx = blockIdx.x >> 8;
    const int mb   = blockIdx.x & 255;

    for (int i = 0; i < 8; ++i) {
        int row = 4 * i + (t >> 6), col = (t & 63) * 4;
        float4 f = *(const float4*)(feats + (mb * 32 + row) * 256 + col);
        *(uint2*)&A[row][col] = make_uint2(f2bpk(f.x, f.y), f2bpk(f.z, f.w));
    }
    __syncthreads();

    const int lane = t & 63, w = t >> 6;
    const int ln15 = lane & 15, quad = lane >> 4;
    const int mt = w & 1, nh = w >> 1;

    bf16x8_t afr[8];
    #pragma unroll
    for (int kk = 0; kk < 8; ++kk)
        afr[kk] = *(const bf16x8_t*)&A[mt * 16 + ln15][kk * 32 + quad * 8];

    const unsigned short* W = wT + widx * 65536;
    const float* bias = (widx == 0) ? bq : (widx == 1) ? bk : bv;
    const float* bn   = (widx == 0) ? bnq : (widx == 1) ? bnk : nullptr;
    unsigned short* dst = qkv + (size_t)widx * 8192 * 256;

    const f32x4_t fzero = {0.f, 0.f, 0.f, 0.f};
    f32x4_t acc[8];
    for (int j = 0; j < 8; ++j) acc[j] = fzero;

    #pragma unroll
    for (int kk = 0; kk < 8; ++kk) {
        #pragma unroll
        for (int j = 0; j < 8; ++j) {
            int nt = nh * 8 + j;
            bf16x8_t bfr = *(const bf16x8_t*)(W + ((nt * 8 + kk) * 64 + lane) * 8);
            acc[j] = __builtin_amdgcn_mfma_f32_16x16x32_bf16(afr[kk], bfr, acc[j], 0, 0, 0);
        }
    }

    float bb[8], sc[8], mu[8], be[8];
    #pragma unroll
    for (int j = 0; j < 8; ++j) {
        int c = (nh * 8 + j) * 16 + ln15;
        bb[j] = bias[c];
        if (bn) {
            sc[j] = bn[c] / sqrtf(bn[768 + c] + BN_EPS);
            be[j] = bn[256 + c];
            mu[j] = bn[512 + c];
        }
    }
    __syncthreads();
    #pragma unroll
    for (int j = 0; j < 8; ++j) {
        int c = (nh * 8 + j) * 16 + ln15;
        float y[4];
        for (int r = 0; r < 4; ++r) {
            y[r] = acc[j][r] + bb[j];
            if (bn) y[r] = fmaxf((y[r] - mu[j]) * sc[j] + be[j], 0.f);
        }
        for (int r = 0; r < 4; r += 2) {
            unsigned int pk = f2bpk(y[r], y[r + 1]);
            A[mt * 16 + quad * 4 + r][c]     = (unsigned short)pk;
            A[mt * 16 + quad * 4 + r + 1][c] = (unsigned short)(pk >> 16);
        }
    }
    __syncthreads();
    {
        int row = t >> 3, cc = (t & 7) * 32;
        #pragma unroll
        for (int j = 0; j < 4; ++j) {
            uint4 v = *(const uint4*)&A[row][cc + 8 * j];
            *(uint4*)(dst + (mb * 32 + row) * 256 + cc + 8 * j) = v;
        }
    }
}

// ---------------------------------------------------------------------------
// K2: fused main. 1 WG = 4 points, wave w owns point w. blk=256, grid=2048.
// ---------------------------------------------------------------------------
__global__ __launch_bounds__(256, 2) void k_main(
    const float* __restrict__ coords,
    const int*   __restrict__ index,
    const unsigned short* __restrict__ qm,
    const unsigned short* __restrict__ km,
    const unsigned short* __restrict__ vm,
    const unsigned short* __restrict__ pmw2F,
    const unsigned short* __restrict__ pbw2F,
    const float* __restrict__ W4,
    const unsigned short* __restrict__ we1TF,
    const float* __restrict__ pm_b2, const float* __restrict__ pb_b2,
    const float* __restrict__ we_b1, const float* __restrict__ we_bn,
    const float* __restrict__ we_w2, const float* __restrict__ we_b2,
    float* __restrict__ out)
{
    __shared__ unsigned short bufR[64][264];   // h0 -> h1 -> pem
    __shared__ unsigned short bufP[64][264];   // peb
    __shared__ float posA[64][4];
    __shared__ float us_[64][8];               // u -> logits -> softmax w
    __shared__ int   rowg_[64];
    __shared__ float we2s[8][8];
    __shared__ float web2[8];

    const int t  = threadIdx.x;
    const int P0 = blockIdx.x * 4;
    const int bb_ = P0 >> 12;
    const int w = t >> 6, lane = t & 63;
    const int ln15 = lane & 15, quad = lane >> 4;
    const int R0 = w * 16;
    const int Pg = P0 + w;

    // ---- per-lane neighbor row (s = ln15) + k prefetch in A-frag layout ----
    const int rg = (bb_ << 12) + index[Pg * 16 + ln15];
    uint4 kpre[8];
    #pragma unroll
    for (int kk = 0; kk < 8; ++kk)
        kpre[kk] = *(const uint4*)(km + rg * 256 + kk * 32 + quad * 8);

    // ---- per-lane folded layer-1 coeffs (4 cols) ----
    const int hc = lane * 4;
    float4 cm[4], cb[4];
    #pragma unroll
    for (int i = 0; i < 4; ++i) {
        cm[i] = ((const float4*)W4)[hc + i];
        cb[i] = ((const float4*)W4)[256 + hc + i];
    }
    // bias for acc init
    float bb0[4], bb1[4];
    #pragma unroll
    for (int ntl = 0; ntl < 4; ++ntl) {
        int c = (w * 4 + ntl) * 16 + ln15;
        bb0[ntl] = pb_b2[c];
        bb1[ntl] = pm_b2[c];
    }

    // ---- per-lane logits-BN fold ----
    const int g8 = ln15 & 7;
    const float swe_r = we_bn[g8] / sqrtf(we_bn[24 + g8] + BN_EPS);
    const float dwe_r = (we_b1[g8] - we_bn[16 + g8]) * swe_r + we_bn[8 + g8];

    // ---- per-wave staging ----
    if (lane < 16) {
        rowg_[R0 + lane] = rg;
        posA[R0 + lane][0] = coords[Pg * 3 + 0] - coords[rg * 3 + 0];
        posA[R0 + lane][1] = coords[Pg * 3 + 1] - coords[rg * 3 + 1];
        posA[R0 + lane][2] = coords[Pg * 3 + 2] - coords[rg * 3 + 2];
        posA[R0 + lane][3] = 0.f;
    }
    if (t < 64) we2s[t >> 3][t & 7] = we_w2[t];
    if (t < 8)  web2[t] = we_b2[t];
    WSYNC();

    // ---- h0 (pb MLP hidden): own 16 rows x 4 cols ----
    #pragma unroll
    for (int m = 0; m < 16; ++m) {
        float4 p = *(const float4*)&posA[R0 + m][0];
        float h0 = fmaxf(p.x * cb[0].x + p.y * cb[0].y + p.z * cb[0].z + cb[0].w, 0.f);
        float h1 = fmaxf(p.x * cb[1].x + p.y * cb[1].y + p.z * cb[1].z + cb[1].w, 0.f);
        float h2 = fmaxf(p.x * cb[2].x + p.y * cb[2].y + p.z * cb[2].z + cb[2].w, 0.f);
        float h3 = fmaxf(p.x * cb[3].x + p.y * cb[3].y + p.z * cb[3].z + cb[3].w, 0.f);
        *(uint2*)&bufR[R0 + m][hc] = make_uint2(f2bpk(h0, h1), f2bpk(h2, h3));
    }
    __syncthreads();                           // B1

    // ---- pass0 MFMA (cooperative M=64, wave N-band): peb, acc init = bias ----
    f32x4_t acc[4][4];
    #pragma unroll
    for (int a = 0; a < 4; ++a)
        for (int mt = 0; mt < 4; ++mt)
            acc[a][mt] = (f32x4_t){bb0[a], bb0[a], bb0[a], bb0[a]};
    #pragma unroll
    for (int kk = 0; kk < 8; ++kk) {
        bf16x8_t afr[4];
        #pragma unroll
        for (int mt = 0; mt < 4; ++mt)
            afr[mt] = *(const bf16x8_t*)&bufR[mt * 16 + ln15][kk * 32 + quad * 8];
        #pragma unroll
        for (int ntl = 0; ntl < 4; ++ntl) {
            int nt = w * 4 + ntl;
            bf16x8_t bfr = *(const bf16x8_t*)(pbw2F + ((nt * 8 + kk) * 64 + lane) * 8);
            #pragma unroll
            for (int mt = 0; mt < 4; ++mt)
                acc[ntl][mt] = __builtin_amdgcn_mfma_f32_16x16x32_bf16(afr[mt], bfr, acc[ntl][mt], 0, 0, 0);
        }
    }
    __syncthreads();                           // B2 (h0 reads done)

    // peb epilogue -> bufP
    #pragma unroll
    for (int ntl = 0; ntl < 4; ++ntl) {
        int c = (w * 4 + ntl) * 16 + ln15;
        for (int mt = 0; mt < 4; ++mt)
            for (int r = 0; r < 4; r += 2) {
                unsigned int pk = f2bpk(acc[ntl][mt][r], acc[ntl][mt][r + 1]);
                bufP[mt * 16 + quad * 4 + r][c]     = (unsigned short)pk;
                bufP[mt * 16 + quad * 4 + r + 1][c] = (unsigned short)(pk >> 16);
            }
    }
    // h1 (pm MLP hidden) -> bufR
    #pragma unroll
    for (int m = 0; m < 16; ++m) {
        float4 p = *(const float4*)&posA[R0 + m][0];
        float h0 = fmaxf(p.x * cm[0].x + p.y * cm[0].y + p.z * cm[0].z + cm[0].w, 0.f);
        float h1 = fmaxf(p.x * cm[1].x + p.y * cm[1].y + p.z * cm[1].z + cm[1].w, 0.f);
        float h2 = fmaxf(p.x * cm[2].x + p.y * cm[2].y + p.z * cm[2].z + cm[2].w, 0.f);
        float h3 = fmaxf(p.x * cm[3].x + p.y * cm[3].y + p.z * cm[3].z + cm[3].w, 0.f);
        *(uint2*)&bufR[R0 + m][hc] = make_uint2(f2bpk(h0, h1), f2bpk(h2, h3));
    }
    __syncthreads();                           // B3

    // ---- pass1 MFMA: pem, acc init = bias ----
    #pragma unroll
    for (int a = 0; a < 4; ++a)
        for (int mt = 0; mt < 4; ++mt)
            acc[a][mt] = (f32x4_t){bb1[a], bb1[a], bb1[a], bb1[a]};
    #pragma unroll
    for (int kk = 0; kk < 8; ++kk) {
        bf16x8_t afr[4];
        #pragma unroll
        for (int mt = 0; mt < 4; ++mt)
            afr[mt] = *(const bf16x8_t*)&bufR[mt * 16 + ln15][kk * 32 + quad * 8];
        #pragma unroll
        for (int ntl = 0; ntl < 4; ++ntl) {
            int nt = w * 4 + ntl;
            bf16x8_t bfr = *(const bf16x8_t*)(pmw2F + ((nt * 8 + kk) * 64 + lane) * 8);
            #pragma unroll
            for (int mt = 0; mt < 4; ++mt)
                acc[ntl][mt] = __builtin_amdgcn_mfma_f32_16x16x32_bf16(afr[mt], bfr, acc[ntl][mt], 0, 0, 0);
        }
    }
    __syncthreads();                           // B4 (h1 reads done)

    // pem epilogue -> bufR
    #pragma unroll
    for (int ntl = 0; ntl < 4; ++ntl) {
        int c = (w * 4 + ntl) * 16 + ln15;
        for (int mt = 0; mt < 4; ++mt)
            for (int r = 0; r < 4; r += 2) {
                unsigned int pk = f2bpk(acc[ntl][mt][r], acc[ntl][mt][r + 1]);
                bufR[mt * 16 + quad * 4 + r][c]     = (unsigned short)pk;
                bufR[mt * 16 + quad * 4 + r + 1][c] = (unsigned short)(pk >> 16);
            }
    }
    __syncthreads();                           // B5 (pem/peb visible)

    // ---- relation + logits fused, in-register A-frags (per wave) ----
    {
        const bf16x8_t bz = {0, 0, 0, 0, 0, 0, 0, 0};
        f32x4_t lacc = {0.f, 0.f, 0.f, 0.f};
        #pragma unroll
        for (int kk = 0; kk < 8; ++kk) {
            int cb8 = kk * 32 + quad * 8;
            uint4 pm4 = *(const uint4*)&bufR[R0 + ln15][cb8];
            uint4 pb4 = *(const uint4*)&bufP[R0 + ln15][cb8];
            uint4 q4  = *(const uint4*)(qm + Pg * 256 + cb8);
            union { uint4 u; bf16x8_t v; } rr;
            rr.u.x = relpair(kpre[kk].x, q4.x, pm4.x, pb4.x);
            rr.u.y = relpair(kpre[kk].y, q4.y, pm4.y, pb4.y);
            rr.u.z = relpair(kpre[kk].z, q4.z, pm4.z, pb4.z);
            rr.u.w = relpair(kpre[kk].w, q4.w, pm4.w, pb4.w);
            bf16x8_t bfr = bz;
            if (ln15 < 8) bfr = *(const bf16x8_t*)(we1TF + ln15 * 256 + cb8);
            lacc = __builtin_amdgcn_mfma_f32_16x16x32_bf16(rr.v, bfr, lacc, 0, 0, 0);
        }
        if (ln15 < 8) {
            #pragma unroll
            for (int r = 0; r < 4; ++r)
                us_[R0 + quad * 4 + r][ln15] = fmaxf(lacc[r] * swe_r + dwe_r, 0.f);
        }
    }
    WSYNC();

    // ---- logits2 = u @ we_w2 + we_b2 (lanes<16, s=lane) ----
    if (lane < 16) {
        float uv[8], l[8];
        #pragma unroll
        for (int gp = 0; gp < 8; ++gp) uv[gp] = us_[R0 + lane][gp];
        #pragma unroll
        for (int g = 0; g < 8; ++g) {
            float x = web2[g];
            for (int gp = 0; gp < 8; ++gp) x += uv[gp] * we2s[gp][g];
            l[g] = x;
        }
        #pragma unroll
        for (int g = 0; g < 8; ++g) us_[R0 + lane][g] = l[g];
    }
    WSYNC();

    // ---- softmax over s (lanes<8, g=lane) ----
    if (lane < 8) {
        int g = lane;
        float mx = -1e30f;
        for (int s = 0; s < 16; ++s) mx = fmaxf(mx, us_[R0 + s][g]);
        float e[16], sum = 0.f;
        for (int s = 0; s < 16; ++s) { e[s] = __expf(us_[R0 + s][g] - mx); sum += e[s]; }
        float inv = 1.f / sum;
        for (int s = 0; s < 16; ++s) us_[R0 + s][g] = e[s] * inv;
    }
    WSYNC();

    // ---- output: out[Pg][c5] = sum_s w[s][g] * (v_g + peb) ----
    {
        int c5 = lane * 4, g = lane >> 3;
        float a0 = 0.f, a1 = 0.f, a2 = 0.f, a3 = 0.f;
        #pragma unroll
        for (int s = 0; s < 16; ++s) {
            int rv = rowg_[R0 + s];
            float wv_ = us_[R0 + s][g];
            uint2 v4 = *(const uint2*)(vm + rv * 256 + c5);
            uint2 p4 = *(const uint2*)&bufP[R0 + s][c5];
            a0 += wv_ * (blo(v4.x) + blo(p4.x));
            a1 += wv_ * (bhi(v4.x) + bhi(p4.x));
            a2 += wv_ * (blo(v4.y) + blo(p4.y));
            a3 += wv_ * (bhi(v4.y) + bhi(p4.y));
        }
        *(float4*)(out + (size_t)Pg * 256 + c5) = make_float4(a0, a1, a2, a3);
    }
}

// ---------------------------------------------------------------------------
extern "C" void kernel_launch(void* const* d_in, const int* in_sizes, int n_in,
                              void* d_out, int out_size, void* d_ws, size_t ws_size,
                              hipStream_t stream)
{
    const float* feats  = (const float*)d_in[0];
    const float* coords = (const float*)d_in[1];
    const int*   index  = (const int*)d_in[2];
    const float* wq     = (const float*)d_in[3];
    const float* bq     = (const float*)d_in[4];
    const float* bnq    = (const float*)d_in[5];
    const float* wk     = (const float*)d_in[6];
    const float* bk     = (const float*)d_in[7];
    const float* bnk    = (const float*)d_in[8];
    const float* wv     = (const float*)d_in[9];
    const float* bv     = (const float*)d_in[10];
    const float* pm_w1  = (const float*)d_in[11];
    const float* pm_b1  = (const float*)d_in[12];
    const float* pm_bn  = (const float*)d_in[13];
    const float* pm_w2  = (const float*)d_in[14];
    const float* pm_b2  = (const float*)d_in[15];
    const float* pb_w1  = (const float*)d_in[16];
    const float* pb_b1  = (const float*)d_in[17];
    const float* pb_bn  = (const float*)d_in[18];
    const float* pb_w2  = (const float*)d_in[19];
    const float* pb_b2  = (const float*)d_in[20];
    const float* we_w1  = (const float*)d_in[21];
    const float* we_b1  = (const float*)d_in[22];
    const float* we_bn  = (const float*)d_in[23];
    const float* we_w2  = (const float*)d_in[24];
    const float* we_b2  = (const float*)d_in[25];

    unsigned short* qkv   = (unsigned short*)d_ws;                    // 12.58 MB
    unsigned short* wsT   = qkv + (size_t)3 * 8192 * 256;             // 640 KB
    float*          W4    = (float*)(wsT + 5 * 65536);                // 8 KB
    unsigned short* we1TF = (unsigned short*)(W4 + 2048);             // 4 KB

    const size_t need = (size_t)13238272 + 8192 + 4096;
    if (ws_size < need) {
        hipMemsetAsync(d_out, 0, (size_t)out_size * 4, stream);
        return;
    }

    k_prep<<<162,  256, 0, stream>>>(wq, wk, wv, pm_w2, pb_w2,
                                     pm_w1, pm_b1, pm_bn,
                                     pb_w1, pb_b1, pb_bn,
                                     we_w1, wsT, W4, we1TF);
    k_qkv <<<768,  256, 0, stream>>>(feats, wsT, bq, bnq, bk, bnk, bv, qkv);
    k_main<<<2048, 256, 0, stream>>>(coords, index,
                                     qkv,
                                     qkv + (size_t)8192 * 256,
                                     qkv + (size_t)2 * 8192 * 256,
                                     wsT + 3 * 65536,
                                     wsT + 4 * 65536,
                                     W4, we1TF,
                                     pm_b2, pb_b2,
                                     we_b1, we_bn, we_w2, we_b2,
                                     (float*)d_out);
}

// Round 12
// 197.476 us; speedup vs baseline: 1.2123x; 1.0222x over previous
//
#include <hip/hip_runtime.h>
#include <hip/hip_bf16.h>

// GroupedVectorSA (gfx950) — ROUND 12: k_main at 512 threads/block (16 waves/CU),
// per-wave work halved, relation K-split across wave pairs. k_prep/k_qkv as R11.

typedef __attribute__((ext_vector_type(8))) short bf16x8_t;
typedef __attribute__((ext_vector_type(4))) float f32x4_t;

#define BN_EPS 1e-5f
#define WSYNC() asm volatile("s_waitcnt lgkmcnt(0)" ::: "memory")

__device__ __forceinline__ float blo(unsigned int v) {
    union { unsigned int u; float f; } x; x.u = v << 16; return x.f;
}
__device__ __forceinline__ float bhi(unsigned int v) {
    union { unsigned int u; float f; } x; x.u = v & 0xffff0000u; return x.f;
}
__device__ __forceinline__ unsigned int fbits(float f) {
    union { float f; unsigned int u; } x; x.f = f; return x.u;
}
__device__ __forceinline__ unsigned short f2b(float f) {      // RNE fp32->bf16
    unsigned int u = fbits(f);
    return (unsigned short)((u + 0x7fffu + ((u >> 16) & 1u)) >> 16);
}
__device__ __forceinline__ unsigned int f2bpk(float a, float b) {  // hw packed cvt
    union { __hip_bfloat162 h; unsigned int u; } x;
    x.h = __float22bfloat162_rn(make_float2(a, b));
    return x.u;
}
__device__ __forceinline__ unsigned int relpair(unsigned int kb, unsigned int qb,
                                                unsigned int pm_, unsigned int pb_) {
    float r0 = (blo(kb) - blo(qb)) * blo(pm_) + blo(pb_);
    float r1 = (bhi(kb) - bhi(qb)) * bhi(pm_) + bhi(pb_);
    return f2bpk(r0, r1);
}

// ---------------------------------------------------------------------------
// K0: blocks 0..159: 5 weights -> bf16 fragment-linear. 160: W4. 161: we1TF.
// ---------------------------------------------------------------------------
__global__ __launch_bounds__(256) void k_prep(
    const float* __restrict__ wq, const float* __restrict__ wk,
    const float* __restrict__ wv, const float* __restrict__ pm2,
    const float* __restrict__ pb2,
    const float* __restrict__ pm_w1, const float* __restrict__ pm_b1,
    const float* __restrict__ pm_bn,
    const float* __restrict__ pb_w1, const float* __restrict__ pb_b1,
    const float* __restrict__ pb_bn,
    const float* __restrict__ we_w1,
    unsigned short* __restrict__ wsT, float* __restrict__ W4,
    unsigned short* __restrict__ we1TF)
{
    const int bid = blockIdx.x, t = threadIdx.x;
    if (bid < 160) {
        __shared__ unsigned short T[32][72];
        const int mat = bid >> 5;
        const int kk  = (bid >> 2) & 7;
        const int ntq = bid & 3;
        const float* s = (mat == 0) ? wq : (mat == 1) ? wk : (mat == 2) ? wv
                         : (mat == 3) ? pm2 : pb2;
        {
            int c = t & 63, r0 = t >> 6;
            for (int i = 0; i < 8; ++i) {
                int r = r0 + i * 4;
                T[r][c] = f2b(s[(kk * 32 + r) * 256 + ntq * 64 + c]);
            }
        }
        __syncthreads();
        {
            int seg = t >> 6, lane = t & 63;
            int col = seg * 16 + (lane & 15);
            int kr  = (lane >> 4) * 8;
            unsigned int v[8];
            #pragma unroll
            for (int j = 0; j < 8; ++j) v[j] = T[kr + j][col];
            uint4 o;
            o.x = v[0] | (v[1] << 16);
            o.y = v[2] | (v[3] << 16);
            o.z = v[4] | (v[5] << 16);
            o.w = v[6] | (v[7] << 16);
            *(uint4*)(wsT + mat * 65536 + (ntq * 4 + seg) * 4096 + kk * 512 + lane * 8) = o;
        }
    } else if (bid == 160) {
        int c = t;
        float s = pm_bn[c] / sqrtf(pm_bn[768 + c] + BN_EPS);
        float4 wm = make_float4(pm_w1[c] * s, pm_w1[256 + c] * s, pm_w1[512 + c] * s,
                                (pm_b1[c] - pm_bn[512 + c]) * s + pm_bn[256 + c]);
        s = pb_bn[c] / sqrtf(pb_bn[768 + c] + BN_EPS);
        float4 wb = make_float4(pb_w1[c] * s, pb_w1[256 + c] * s, pb_w1[512 + c] * s,
                                (pb_b1[c] - pb_bn[512 + c]) * s + pb_bn[256 + c]);
        ((float4*)W4)[c]       = wm;
        ((float4*)W4)[256 + c] = wb;
    } else {
        for (int j = 0; j < 8; ++j) {
            int e = t * 8 + j;
            int g = e >> 8, c = e & 255;
            we1TF[g * 256 + c] = f2b(we_w1[c * 8 + g]);
        }
    }
}

// ---------------------------------------------------------------------------
// K1: q/k/v GEMM. grid=768, blk=256. (unchanged from R11)
// ---------------------------------------------------------------------------
__global__ __launch_bounds__(256) void k_qkv(
    const float* __restrict__ feats,
    const unsigned short* __restrict__ wT,
    const float* __restrict__ bq, const float* __restrict__ bnq,
    const float* __restrict__ bk, const float* __restrict__ bnk,
    const float* __restrict__ bv,
    unsigned short* __restrict__ qkv)
{
    __shared__ unsigned short A[32][264];
    const int t    = threadIdx.x;
    const int widx = blockIdx.x >> 8;
    const int mb   = blockIdx.x & 255;

    for (int i = 0; i < 8; ++i) {
        int row = 4 * i + (t >> 6), col = (t & 63) * 4;
        float4 f = *(const float4*)(feats + (mb * 32 + row) * 256 + col);
        *(uint2*)&A[row][col] = make_uint2(f2bpk(f.x, f.y), f2bpk(f.z, f.w));
    }
    __syncthreads();

    const int lane = t & 63, w = t >> 6;
    const int ln15 = lane & 15, quad = lane >> 4;
    const int mt = w & 1, nh = w >> 1;

    bf16x8_t afr[8];
    #pragma unroll
    for (int kk = 0; kk < 8; ++kk)
        afr[kk] = *(const bf16x8_t*)&A[mt * 16 + ln15][kk * 32 + quad * 8];

    const unsigned short* W = wT + widx * 65536;
    const float* bias = (widx == 0) ? bq : (widx == 1) ? bk : bv;
    const float* bn   = (widx == 0) ? bnq : (widx == 1) ? bnk : nullptr;
    unsigned short* dst = qkv + (size_t)widx * 8192 * 256;

    f32x4_t acc[8];
    for (int j = 0; j < 8; ++j) acc[j] = (f32x4_t){0.f, 0.f, 0.f, 0.f};

    #pragma unroll
    for (int kk = 0; kk < 8; ++kk) {
        #pragma unroll
        for (int j = 0; j < 8; ++j) {
            int nt = nh * 8 + j;
            bf16x8_t bfr = *(const bf16x8_t*)(W + ((nt * 8 + kk) * 64 + lane) * 8);
            acc[j] = __builtin_amdgcn_mfma_f32_16x16x32_bf16(afr[kk], bfr, acc[j], 0, 0, 0);
        }
    }

    float bb[8], sc[8], mu[8], be[8];
    #pragma unroll
    for (int j = 0; j < 8; ++j) {
        int c = (nh * 8 + j) * 16 + ln15;
        bb[j] = bias[c];
        if (bn) {
            sc[j] = bn[c] / sqrtf(bn[768 + c] + BN_EPS);
            be[j] = bn[256 + c];
            mu[j] = bn[512 + c];
        }
    }
    __syncthreads();
    #pragma unroll
    for (int j = 0; j < 8; ++j) {
        int c = (nh * 8 + j) * 16 + ln15;
        float y[4];
        for (int r = 0; r < 4; ++r) {
            y[r] = acc[j][r] + bb[j];
            if (bn) y[r] = fmaxf((y[r] - mu[j]) * sc[j] + be[j], 0.f);
        }
        for (int r = 0; r < 4; r += 2) {
            unsigned int pk = f2bpk(y[r], y[r + 1]);
            A[mt * 16 + quad * 4 + r][c]     = (unsigned short)pk;
            A[mt * 16 + quad * 4 + r + 1][c] = (unsigned short)(pk >> 16);
        }
    }
    __syncthreads();
    {
        int row = t >> 3, cc = (t & 7) * 32;
        #pragma unroll
        for (int j = 0; j < 4; ++j) {
            uint4 v = *(const uint4*)&A[row][cc + 8 * j];
            *(uint4*)(dst + (mb * 32 + row) * 256 + cc + 8 * j) = v;
        }
    }
}

// ---------------------------------------------------------------------------
// K2: fused main. 512 threads (8 waves), 4 points/block, wave pair per point.
// grid=2048. LDS ~75.4KB -> 2 blocks/CU -> 16 waves/CU.
// ---------------------------------------------------------------------------
__global__ __launch_bounds__(512, 4) void k_main(
    const float* __restrict__ coords,
    const int*   __restrict__ index,
    const unsigned short* __restrict__ qm,
    const unsigned short* __restrict__ km,
    const unsigned short* __restrict__ vm,
    const unsigned short* __restrict__ pmw2F,
    const unsigned short* __restrict__ pbw2F,
    const float* __restrict__ W4,
    const unsigned short* __restrict__ we1TF,
    const float* __restrict__ pm_b2, const float* __restrict__ pb_b2,
    const float* __restrict__ we_b1, const float* __restrict__ we_bn,
    const float* __restrict__ we_w2, const float* __restrict__ we_b2,
    float* __restrict__ out)
{
    __shared__ unsigned short bufR[64][264];   // h0 -> h1 -> pem
    __shared__ unsigned short bufP[64][264];   // peb
    __shared__ float posA[64][4];
    __shared__ float usP[2][64][8];            // partial logits (K-split halves)
    __shared__ float us_[64][8];               // logits -> softmax w
    __shared__ int   rowg_[64];
    __shared__ float we2s[8][8];
    __shared__ float web2[8], swe8[8], dwe8[8];

    const int t   = threadIdx.x;
    const int P0  = blockIdx.x * 4;
    const int bb_ = P0 >> 12;
    const int w = t >> 6, lane = t & 63;
    const int ln15 = lane & 15, quad = lane >> 4;
    const int p   = w >> 1, sub = w & 1;       // wave pair (2p, 2p+1) owns point p
    const int R0  = p * 16;
    const int Pg  = P0 + p;

    // ---- per-lane neighbor row (s=ln15) + k prefetch, K-half sub ----
    const int rg = (bb_ << 12) + index[Pg * 16 + ln15];
    uint4 kpre[4];
    #pragma unroll
    for (int kk = 0; kk < 4; ++kk)
        kpre[kk] = *(const uint4*)(km + rg * 256 + (sub * 4 + kk) * 32 + quad * 8);

    // ---- per-wave pos/rowg staging: own 8 rows (lanes<8) ----
    if (lane < 8) {
        int m  = w * 8 + lane;
        int Pr = P0 + (m >> 4);
        int rs = (bb_ << 12) + index[Pr * 16 + (m & 15)];
        rowg_[m]   = rs;
        posA[m][0] = coords[Pr * 3 + 0] - coords[rs * 3 + 0];
        posA[m][1] = coords[Pr * 3 + 1] - coords[rs * 3 + 1];
        posA[m][2] = coords[Pr * 3 + 2] - coords[rs * 3 + 2];
        posA[m][3] = 0.f;
    }
    if (t < 64) we2s[t >> 3][t & 7] = we_w2[t];
    if (t < 8) {
        float s = we_bn[t] / sqrtf(we_bn[24 + t] + BN_EPS);
        swe8[t] = s;
        dwe8[t] = (we_b1[t] - we_bn[16 + t]) * s + we_bn[8 + t];
        web2[t] = we_b2[t];
    }
    WSYNC();

    const int hc = lane * 4;                   // h-build: 4 cols per lane
    const int hm = w * 8;                      // and 8 rows per wave

    // ---- h0 (pb hidden) -> bufR (own rows -> wave-local) ----
    {
        float4 c0 = ((const float4*)W4)[256 + hc];
        float4 c1 = ((const float4*)W4)[256 + hc + 1];
        float4 c2 = ((const float4*)W4)[256 + hc + 2];
        float4 c3 = ((const float4*)W4)[256 + hc + 3];
        #pragma unroll
        for (int m = 0; m < 8; ++m) {
            float4 pp = *(const float4*)&posA[hm + m][0];
            float h0 = fmaxf(pp.x * c0.x + pp.y * c0.y + pp.z * c0.z + c0.w, 0.f);
            float h1 = fmaxf(pp.x * c1.x + pp.y * c1.y + pp.z * c1.z + c1.w, 0.f);
            float h2 = fmaxf(pp.x * c2.x + pp.y * c2.y + pp.z * c2.z + c2.w, 0.f);
            float h3 = fmaxf(pp.x * c3.x + pp.y * c3.y + pp.z * c3.z + c3.w, 0.f);
            *(uint2*)&bufR[hm + m][hc] = make_uint2(f2bpk(h0, h1), f2bpk(h2, h3));
        }
    }
    __syncthreads();                           // B1

    // ---- pass0 MFMA: peb. wave N-band = nt w*2..w*2+1, acc init = bias ----
    f32x4_t acc[2][4];
    {
        float b0 = pb_b2[(w * 2    ) * 16 + ln15];
        float b1 = pb_b2[(w * 2 + 1) * 16 + ln15];
        for (int mt = 0; mt < 4; ++mt) {
            acc[0][mt] = (f32x4_t){b0, b0, b0, b0};
            acc[1][mt] = (f32x4_t){b1, b1, b1, b1};
        }
    }
    #pragma unroll
    for (int kk = 0; kk < 8; ++kk) {
        bf16x8_t afr[4];
        #pragma unroll
        for (int mt = 0; mt < 4; ++mt)
            afr[mt] = *(const bf16x8_t*)&bufR[mt * 16 + ln15][kk * 32 + quad * 8];
        #pragma unroll
        for (int ntl = 0; ntl < 2; ++ntl) {
            int nt = w * 2 + ntl;
            bf16x8_t bfr = *(const bf16x8_t*)(pbw2F + ((nt * 8 + kk) * 64 + lane) * 8);
            #pragma unroll
            for (int mt = 0; mt < 4; ++mt)
                acc[ntl][mt] = __builtin_amdgcn_mfma_f32_16x16x32_bf16(afr[mt], bfr, acc[ntl][mt], 0, 0, 0);
        }
    }
    __syncthreads();                           // B2 (h0 reads done)

    // peb epilogue -> bufP
    #pragma unroll
    for (int ntl = 0; ntl < 2; ++ntl) {
        int c = (w * 2 + ntl) * 16 + ln15;
        for (int mt = 0; mt < 4; ++mt)
            for (int r = 0; r < 4; r += 2) {
                unsigned int pk = f2bpk(acc[ntl][mt][r], acc[ntl][mt][r + 1]);
                bufP[mt * 16 + quad * 4 + r][c]     = (unsigned short)pk;
                bufP[mt * 16 + quad * 4 + r + 1][c] = (unsigned short)(pk >> 16);
            }
    }
    // h1 (pm hidden) -> bufR
    {
        float4 c0 = ((const float4*)W4)[hc];
        float4 c1 = ((const float4*)W4)[hc + 1];
        float4 c2 = ((const float4*)W4)[hc + 2];
        float4 c3 = ((const float4*)W4)[hc + 3];
        #pragma unroll
        for (int m = 0; m < 8; ++m) {
            float4 pp = *(const float4*)&posA[hm + m][0];
            float h0 = fmaxf(pp.x * c0.x + pp.y * c0.y + pp.z * c0.z + c0.w, 0.f);
            float h1 = fmaxf(pp.x * c1.x + pp.y * c1.y + pp.z * c1.z + c1.w, 0.f);
            float h2 = fmaxf(pp.x * c2.x + pp.y * c2.y + pp.z * c2.z + c2.w, 0.f);
            float h3 = fmaxf(pp.x * c3.x + pp.y * c3.y + pp.z * c3.z + c3.w, 0.f);
            *(uint2*)&bufR[hm + m][hc] = make_uint2(f2bpk(h0, h1), f2bpk(h2, h3));
        }
    }
    __syncthreads();                           // B3

    // ---- pass1 MFMA: pem, acc init = bias ----
    {
        float b0 = pm_b2[(w * 2    ) * 16 + ln15];
        float b1 = pm_b2[(w * 2 + 1) * 16 + ln15];
        for (int mt = 0; mt < 4; ++mt) {
            acc[0][mt] = (f32x4_t){b0, b0, b0, b0};
            acc[1][mt] = (f32x4_t){b1, b1, b1, b1};
        }
    }
    #pragma unroll
    for (int kk = 0; kk < 8; ++kk) {
        bf16x8_t afr[4];
        #pragma unroll
        for (int mt = 0; mt < 4; ++mt)
            afr[mt] = *(const bf16x8_t*)&bufR[mt * 16 + ln15][kk * 32 + quad * 8];
        #pragma unroll
        for (int ntl = 0; ntl < 2; ++ntl) {
            int nt = w * 2 + ntl;
            bf16x8_t bfr = *(const bf16x8_t*)(pmw2F + ((nt * 8 + kk) * 64 + lane) * 8);
            #pragma unroll
            for (int mt = 0; mt < 4; ++mt)
                acc[ntl][mt] = __builtin_amdgcn_mfma_f32_16x16x32_bf16(afr[mt], bfr, acc[ntl][mt], 0, 0, 0);
        }
    }
    __syncthreads();                           // B4 (h1 reads done)

    // pem epilogue -> bufR
    #pragma unroll
    for (int ntl = 0; ntl < 2; ++ntl) {
        int c = (w * 2 + ntl) * 16 + ln15;
        for (int mt = 0; mt < 4; ++mt)
            for (int r = 0; r < 4; r += 2) {
                unsigned int pk = f2bpk(acc[ntl][mt][r], acc[ntl][mt][r + 1]);
                bufR[mt * 16 + quad * 4 + r][c]     = (unsigned short)pk;
                bufR[mt * 16 + quad * 4 + r + 1][c] = (unsigned short)(pk >> 16);
            }
    }
    __syncthreads();                           // B5 (pem/peb visible)

    // ---- relation + partial logits (K-half = sub), in registers ----
    {
        const bf16x8_t bz = {0, 0, 0, 0, 0, 0, 0, 0};
        f32x4_t lacc = {0.f, 0.f, 0.f, 0.f};
        #pragma unroll
        for (int kk = 0; kk < 4; ++kk) {
            int cb8 = (sub * 4 + kk) * 32 + quad * 8;
            uint4 pm4 = *(const uint4*)&bufR[R0 + ln15][cb8];
            uint4 pb4 = *(const uint4*)&bufP[R0 + ln15][cb8];
            uint4 q4  = *(const uint4*)(qm + Pg * 256 + cb8);
            union { uint4 u; bf16x8_t v; } rr;
            rr.u.x = relpair(kpre[kk].x, q4.x, pm4.x, pb4.x);
            rr.u.y = relpair(kpre[kk].y, q4.y, pm4.y, pb4.y);
            rr.u.z = relpair(kpre[kk].z, q4.z, pm4.z, pb4.z);
            rr.u.w = relpair(kpre[kk].w, q4.w, pm4.w, pb4.w);
            bf16x8_t bfr = bz;
            if (ln15 < 8) bfr = *(const bf16x8_t*)(we1TF + ln15 * 256 + cb8);
            lacc = __builtin_amdgcn_mfma_f32_16x16x32_bf16(rr.v, bfr, lacc, 0, 0, 0);
        }
        if (ln15 < 8) {
            #pragma unroll
            for (int r = 0; r < 4; ++r)
                usP[sub][R0 + quad * 4 + r][ln15] = lacc[r];
        }
    }
    __syncthreads();                           // B6 (partials visible)

    // ---- combine + BN/relu + logits2 (even wave, lanes<16 = s) ----
    if (sub == 0 && lane < 16) {
        int s = lane;
        float uv[8], l[8];
        #pragma unroll
        for (int g = 0; g < 8; ++g) {
            float x = usP[0][R0 + s][g] + usP[1][R0 + s][g];
            uv[g] = fmaxf(x * swe8[g] + dwe8[g], 0.f);
        }
        #pragma unroll
        for (int g = 0; g < 8; ++g) {
            float x = web2[g];
            for (int gp = 0; gp < 8; ++gp) x += uv[gp] * we2s[gp][g];
            l[g] = x;
        }
        #pragma unroll
        for (int g = 0; g < 8; ++g) us_[R0 + s][g] = l[g];
    }
    WSYNC();

    // ---- softmax over s (even wave, lanes<8 = g) ----
    if (sub == 0 && lane < 8) {
        int g = lane;
        float mx = -1e30f;
        for (int s = 0; s < 16; ++s) mx = fmaxf(mx, us_[R0 + s][g]);
        float e[16], sum = 0.f;
        for (int s = 0; s < 16; ++s) { e[s] = __expf(us_[R0 + s][g] - mx); sum += e[s]; }
        float inv = 1.f / sum;
        for (int s = 0; s < 16; ++s) us_[R0 + s][g] = e[s] * inv;
    }
    __syncthreads();                           // B7 (softmax visible to wave pair)

    // ---- output: wave pair = 128 lanes, 2 cols each ----
    {
        int idx2 = sub * 64 + lane;
        int c5 = idx2 * 2, g = c5 >> 5;
        float a0 = 0.f, a1 = 0.f;
        #pragma unroll
        for (int s = 0; s < 16; ++s) {
            int rv = rowg_[R0 + s];
            float wv_ = us_[R0 + s][g];
            unsigned int v2 = *(const unsigned int*)(vm + rv * 256 + c5);
            unsigned int p2 = *(const unsigned int*)&bufP[R0 + s][c5];
            a0 += wv_ * (blo(v2) + blo(p2));
            a1 += wv_ * (bhi(v2) + bhi(p2));
        }
        *(float2*)(out + (size_t)Pg * 256 + c5) = make_float2(a0, a1);
    }
}

// ---------------------------------------------------------------------------
extern "C" void kernel_launch(void* const* d_in, const int* in_sizes, int n_in,
                              void* d_out, int out_size, void* d_ws, size_t ws_size,
                              hipStream_t stream)
{
    const float* feats  = (const float*)d_in[0];
    const float* coords = (const float*)d_in[1];
    const int*   index  = (const int*)d_in[2];
    const float* wq     = (const float*)d_in[3];
    const float* bq     = (const float*)d_in[4];
    const float* bnq    = (const float*)d_in[5];
    const float* wk     = (const float*)d_in[6];
    const float* bk     = (const float*)d_in[7];
    const float* bnk    = (const float*)d_in[8];
    const float* wv     = (const float*)d_in[9];
    const float* bv     = (const float*)d_in[10];
    const float* pm_w1  = (const float*)d_in[11];
    const float* pm_b1  = (const float*)d_in[12];
    const float* pm_bn  = (const float*)d_in[13];
    const float* pm_w2  = (const float*)d_in[14];
    const float* pm_b2  = (const float*)d_in[15];
    const float* pb_w1  = (const float*)d_in[16];
    const float* pb_b1  = (const float*)d_in[17];
    const float* pb_bn  = (const float*)d_in[18];
    const float* pb_w2  = (const float*)d_in[19];
    const float* pb_b2  = (const float*)d_in[20];
    const float* we_w1  = (const float*)d_in[21];
    const float* we_b1  = (const float*)d_in[22];
    const float* we_bn  = (const float*)d_in[23];
    const float* we_w2  = (const float*)d_in[24];
    const float* we_b2  = (const float*)d_in[25];

    unsigned short* qkv   = (unsigned short*)d_ws;
    unsigned short* wsT   = qkv + (size_t)3 * 8192 * 256;
    float*          W4    = (float*)(wsT + 5 * 65536);
    unsigned short* we1TF = (unsigned short*)(W4 + 2048);

    const size_t need = (size_t)13238272 + 8192 + 4096;
    if (ws_size < need) {
        hipMemsetAsync(d_out, 0, (size_t)out_size * 4, stream);
        return;
    }

    k_prep<<<162,  256, 0, stream>>>(wq, wk, wv, pm_w2, pb_w2,
                                     pm_w1, pm_b1, pm_bn,
                                     pb_w1, pb_b1, pb_bn,
                                     we_w1, wsT, W4, we1TF);
    k_qkv <<<768,  256, 0, stream>>>(feats, wsT, bq, bnq, bk, bnk, bv, qkv);
    k_main<<<2048, 512, 0, stream>>>(coords, index,
                                     qkv,
                                     qkv + (size_t)8192 * 256,
                                     qkv + (size_t)2 * 8192 * 256,
                                     wsT + 3 * 65536,
                                     wsT + 4 * 65536,
                                     W4, we1TF,
                                     pm_b2, pb_b2,
                                     we_b1, we_bn, we_w2, we_b2,
                                     (float*)d_out);
}